// Round 5
// baseline (303.533 us; speedup 1.0000x reference)
//
#include <hip/hip_runtime.h>

#define S_LEN 2048
#define EMB 2048
#define NH 16
#define NKV 4
#define HD 128
#define WINDOW 1024
#define BATCH 2

typedef _Float16 half8 __attribute__((ext_vector_type(8)));
typedef _Float16 half4 __attribute__((ext_vector_type(4)));
typedef float f32x4 __attribute__((ext_vector_type(4)));

#define MFMA16(a, b, c) __builtin_amdgcn_mfma_f32_16x16x32_f16((a), (b), (c), 0, 0, 0)

// async 16B global->LDS (DMA, no VGPR roundtrip).
__device__ __forceinline__ void gload16(const void* g, void* l) {
  __builtin_amdgcn_global_load_lds(
      (const __attribute__((address_space(1))) unsigned int*)g,
      (__attribute__((address_space(3))) unsigned int*)l, 16, 0, 0);
}

// ---------------------------------------------------------------------------
// One-shot fp32 -> fp16 convert of x, Wq, Wk, Wv, Wo into ws.
// ---------------------------------------------------------------------------
__global__ __launch_bounds__(256)
void convert_all(const float* __restrict__ x, const float* __restrict__ wq,
                 const float* __restrict__ wk, const float* __restrict__ wv,
                 const float* __restrict__ wo, _Float16* __restrict__ dst) {
  size_t i = (size_t)blockIdx.x * 256 + threadIdx.x;  // 8-elem unit index
  const float* src; size_t u; size_t dbase;
  if (i < 1048576)      { src = x;  u = i;           dbase = 0; }
  else if (i < 1572864) { src = wq; u = i - 1048576; dbase = 8388608; }
  else if (i < 1703936) { src = wk; u = i - 1572864; dbase = 12582912; }
  else if (i < 1835008) { src = wv; u = i - 1703936; dbase = 13631488; }
  else                  { src = wo; u = i - 1835008; dbase = 14680064; }
  f32x4 a = *(const f32x4*)(src + u * 8);
  f32x4 b = *(const f32x4*)(src + u * 8 + 4);
  half8 h = { (_Float16)a[0], (_Float16)a[1], (_Float16)a[2], (_Float16)a[3],
              (_Float16)b[0], (_Float16)b[1], (_Float16)b[2], (_Float16)b[3] };
  *(half8*)(dst + dbase + u * 8) = h;
}

// ---------------------------------------------------------------------------
// Fused QKV GEMM v2: BK=32, DOUBLE-BUFFERED LDS (2x8KB per operand = 32 KB),
// SINGLE barrier per k-iter: the vmcnt(0) drain before s_barrier waits on a
// DMA issued one full iteration earlier (already landed) instead of one
// issued moments before. XOR-swizzle (chunk^row&3) keeps frag reads
// bank-balanced. V written DIRECTLY in V^T [d][s] layout (kills transpose_v).
// ---------------------------------------------------------------------------
__global__ __launch_bounds__(256)
void qkv_gemm(const _Float16* __restrict__ x16, const _Float16* __restrict__ Wq16,
              const _Float16* __restrict__ Wk16, const _Float16* __restrict__ Wv16,
              _Float16* __restrict__ Qh, _Float16* __restrict__ Kr,
              _Float16* __restrict__ Vt) {
  __shared__ _Float16 Asm[2][128 * 32];
  __shared__ _Float16 Bsm[2][128 * 32];
  const int K = EMB;
  int m0 = blockIdx.y * 128, n0 = blockIdx.x * 128;
  const _Float16* Wp; int c0, sel;
  if (n0 < 2048)      { Wp = Wq16; c0 = n0;        sel = 0; }
  else if (n0 < 2560) { Wp = Wk16; c0 = n0 - 2048; sel = 1; }
  else                { Wp = Wv16; c0 = n0 - 2560; sel = 2; }

  int t = threadIdx.x, lane = t & 63, w = t >> 6;
  int l15 = lane & 15, quad = lane >> 4;
  int wm = (w >> 1) * 64, wn = (w & 1) * 64;

  auto stage = [&](int kt, int p) {
#pragma unroll
    for (int i = 0; i < 2; ++i) {
      int u = t + 256 * i;                 // 0..511 = 128 rows x 4 chunks
      int row = u >> 2, cc = u & 3, g = cc ^ (row & 3);
      gload16(x16 + (size_t)(m0 + row) * K + kt + g * 8, (char*)Asm[p] + (size_t)u * 16);
      gload16(Wp + (size_t)(c0 + row) * K + kt + g * 8, (char*)Bsm[p] + (size_t)u * 16);
    }
  };

  f32x4 acc[4][4] = {};
  stage(0, 0);
  for (int it = 0; it < 64; ++it) {
    int p = it & 1;
    __syncthreads();                       // drains DMA(it) issued last iter
    if (it < 63) stage((it + 1) * 32, 1 - p);
    half8 af[4], bf[4];
#pragma unroll
    for (int i = 0; i < 4; ++i) {
      int row = wm + i * 16 + l15;
      af[i] = *(const half8*)&Asm[p][row * 32 + ((quad ^ (row & 3)) << 3)];
    }
#pragma unroll
    for (int i = 0; i < 4; ++i) {
      int row = wn + i * 16 + l15;
      bf[i] = *(const half8*)&Bsm[p][row * 32 + ((quad ^ (row & 3)) << 3)];
    }
#pragma unroll
    for (int mi = 0; mi < 4; ++mi)
#pragma unroll
      for (int ni = 0; ni < 4; ++ni)
        acc[mi][ni] = MFMA16(af[mi], bf[ni], acc[mi][ni]);
  }
#pragma unroll
  for (int mi = 0; mi < 4; ++mi)
#pragma unroll
    for (int ni = 0; ni < 4; ++ni)
#pragma unroll
      for (int r = 0; r < 4; ++r) {
        int row = m0 + wm + mi * 16 + quad * 4 + r;
        int col = c0 + wn + ni * 16 + l15;
        _Float16 val = (_Float16)acc[mi][ni][r];
        if (sel == 0) {
          Qh[(size_t)row * 2048 + col] = val;
        } else {
          int b = row >> 11, s = row & 2047, kvh = col >> 7, d = col & 127;
          if (sel == 1)
            Kr[((size_t)(b * NKV + kvh) * S_LEN + s) * HD + d] = val;
          else
            Vt[((size_t)(b * NKV + kvh) * HD + d) * S_LEN + s] = val;  // V^T direct
        }
      }
}

// ---------------------------------------------------------------------------
// RoPE K in-place (head-major). cos[d+64]==cos[d].
// ---------------------------------------------------------------------------
__global__ __launch_bounds__(256)
void rope_k(_Float16* __restrict__ Kr, const float* __restrict__ cosT,
            const float* __restrict__ sinT) {
  int t = threadIdx.x;
  int row = blockIdx.x * 32 + (t >> 3);   // (b*NKV+kvh)*S + s
  int s = row & (S_LEN - 1);
  int d0 = (t & 7) * 8;
  _Float16* p = Kr + (size_t)row * HD;
  half8 lo = *(half8*)(p + d0);
  half8 hi = *(half8*)(p + d0 + 64);
  float cv[8], sv[8];
  *(f32x4*)&cv[0] = *(const f32x4*)(cosT + (size_t)s * HD + d0);
  *(f32x4*)&cv[4] = *(const f32x4*)(cosT + (size_t)s * HD + d0 + 4);
  *(f32x4*)&sv[0] = *(const f32x4*)(sinT + (size_t)s * HD + d0);
  *(f32x4*)&sv[4] = *(const f32x4*)(sinT + (size_t)s * HD + d0 + 4);
  half8 rlo, rhi;
#pragma unroll
  for (int u = 0; u < 8; ++u) {
    float l = (float)lo[u], h = (float)hi[u];
    rlo[u] = (_Float16)(l * cv[u] - h * sv[u]);
    rhi[u] = (_Float16)(h * cv[u] + l * sv[u]);
  }
  *(half8*)(p + d0) = rlo;
  *(half8*)(p + d0 + 64) = rhi;
}

// ---------------------------------------------------------------------------
// Flash attention v4: single-barrier software pipeline. K and V^T tiles are
// FULLY double-buffered (32+32 KB); DMA for tile t+1 is issued right after
// the barrier that publishes tile t, so each barrier's vmcnt(0) drain waits
// on a DMA that has had a whole tile's compute to land. P lives in a
// B-frag-layout LDS buffer (16 KB total: per-wave, per-group, [chunk][lane][j])
// -> conflict-free half4 writes, contiguous half8 reads, no padding.
// LDS = 80 KB exactly -> 2 blocks/CU. Transposed S^T=K Q^T per-lane softmax.
// ---------------------------------------------------------------------------
__global__ __launch_bounds__(256, 2)
void attn_fused(const _Float16* Qh, const _Float16* __restrict__ Kr,
                const _Float16* __restrict__ Vt, const float* __restrict__ cosT,
                const float* __restrict__ sinT, _Float16* Oh) {
  const float SL2E = 0.08838834764831843f * 1.4426950408889634f;
  int c = blockIdx.x & 255, half = blockIdx.x >> 8;
  int h = c & 15, j = c >> 4;
  int qt = half ? (15 - j) : j;            // heavy/light pairing per CU
  int b = half;
  int kvh = h >> 2;
  int q0 = qt * 128;
  int t = threadIdx.x, lane = t & 63, w = t >> 6;
  int l15 = lane & 15, quad = lane >> 4;

  __shared__ _Float16 Ksm[2][64 * 128];    // 2 x 16 KB, swizzled [k][chunk^k]
  __shared__ _Float16 Vsm[2][128 * 64];    // 2 x 16 KB, swizzled [d][chunk^d]
  __shared__ _Float16 PB[4][2][2][64 * 8]; // 16 KB: [wave][grp][chunk][lane*8+j]

  int qw0 = q0 + w * 32;

  // ---- Q B-frags for both groups + RoPE + fold scale*log2e ----
  half8 qf[2][4];
#pragma unroll
  for (int g = 0; g < 2; ++g) {
    int qi = qw0 + g * 16 + l15;
    const _Float16* qrow = Qh + (size_t)(b * S_LEN + qi) * EMB + h * HD;
    const float* crow = cosT + (size_t)qi * HD;
    const float* srow = sinT + (size_t)qi * HD;
    float qv[4][8], cv[2][8], sv[2][8];
#pragma unroll
    for (int kc = 0; kc < 4; ++kc) {
      half8 q8 = *(const half8*)(qrow + kc * 32 + quad * 8);
#pragma unroll
      for (int jj = 0; jj < 8; ++jj) qv[kc][jj] = (float)q8[jj];
    }
#pragma unroll
    for (int kc = 0; kc < 2; ++kc) {
      int d0 = kc * 32 + quad * 8;
      *(f32x4*)&cv[kc][0] = *(const f32x4*)(crow + d0);
      *(f32x4*)&cv[kc][4] = *(const f32x4*)(crow + d0 + 4);
      *(f32x4*)&sv[kc][0] = *(const f32x4*)(srow + d0);
      *(f32x4*)&sv[kc][4] = *(const f32x4*)(srow + d0 + 4);
    }
#pragma unroll
    for (int kc = 0; kc < 4; ++kc)
#pragma unroll
      for (int jj = 0; jj < 8; ++jj) {
        float rot = (kc < 2) ? -qv[kc + 2][jj] : qv[kc - 2][jj];
        qf[g][kc][jj] = (_Float16)((qv[kc][jj] * cv[kc & 1][jj] + rot * sv[kc & 1][jj]) * SL2E);
      }
  }

  const _Float16* khead = Kr + (size_t)(b * NKV + kvh) * S_LEN * HD;
  const _Float16* vhead = Vt + (size_t)(b * NKV + kvh) * HD * S_LEN;

  auto stage = [&](int kt, int p) {
    int k0 = kt * 64;
#pragma unroll
    for (int i = 0; i < 4; ++i) {
      int u = t + 256 * i;
      int r = u >> 4, cc = u & 15;
      gload16(khead + (((size_t)(k0 + r)) << 7) + ((cc ^ (r & 15)) << 3),
              (char*)Ksm[p] + (size_t)u * 16);
    }
#pragma unroll
    for (int i = 0; i < 4; ++i) {
      int u = t + 256 * i;
      int d = u >> 3, cc = u & 7;
      gload16(vhead + (((size_t)d) << 11) + k0 + ((cc ^ (d & 7)) << 3),
              (char*)Vsm[p] + (size_t)u * 16);
    }
  };

  f32x4 oacc[2][8] = {};
  float l_r[2] = {0.f, 0.f};

  int kt_lo = (q0 >= WINDOW) ? ((q0 - (WINDOW - 1)) >> 6) : 0;
  int kt_hi = qt * 2 + 1;

  stage(kt_lo, 0);
  for (int kt = kt_lo; kt <= kt_hi; ++kt) {
    int p = (kt - kt_lo) & 1;
    int k0 = kt * 64;
    __syncthreads();                        // drains DMA(kt); frees buf 1-p
    if (kt < kt_hi) stage(kt + 1, 1 - p);   // overlaps all of compute below

    // ---- S^T = K Q^T : K A-frags from LDS, shared across both q-groups ----
    f32x4 sfr[2][4];
#pragma unroll
    for (int nb = 0; nb < 4; ++nb) {
      int r = nb * 16 + l15;
      half8 kf[4];
#pragma unroll
      for (int dc = 0; dc < 4; ++dc) {
        int cw = dc * 4 + quad;
        kf[dc] = *(const half8*)&Ksm[p][r * 128 + ((cw ^ l15) << 3)];
      }
      f32x4 s0 = {0.f, 0.f, 0.f, 0.f}, s1 = {0.f, 0.f, 0.f, 0.f};
#pragma unroll
      for (int dc = 0; dc < 4; ++dc) {
        s0 = MFMA16(kf[dc], qf[0][dc], s0);
        s1 = MFMA16(kf[dc], qf[1][dc], s1);
      }
      sfr[0][nb] = s0; sfr[1][nb] = s1;
    }

    // ---- mask + exp2 (no max) + per-lane l + P straight to B-frag LDS ----
#pragma unroll
    for (int g = 0; g < 2; ++g) {
      int qi = qw0 + g * 16 + l15;
#pragma unroll
      for (int nb = 0; nb < 4; ++nb) {
        half4 ph;
#pragma unroll
        for (int r = 0; r < 4; ++r) {
          int key = k0 + nb * 16 + quad * 4 + r;
          int dd = qi - key;
          float sv = (dd >= 0 && dd < WINDOW) ? sfr[g][nb][r] : -1e4f;
          float pv = __builtin_amdgcn_exp2f(fminf(sv, 14.0f));
          l_r[g] += pv;
          ph[r] = (_Float16)pv;
        }
        // element (q=l15, key=16nb+quad*4+r) -> chunk nb>>1,
        // dest lane = l15 + 16*(2*(nb&1)+(quad>>1)), j = (quad&1)*4+r
        *(half4*)&PB[w][g][nb >> 1]
            [((l15 + 16 * (((nb & 1) << 1) + (quad >> 1))) << 3) + ((quad & 1) << 2)] = ph;
      }
    }

    // ---- P^T B-frags: contiguous half8 per lane ----
    half8 pf[2][2];
#pragma unroll
    for (int g = 0; g < 2; ++g) {
      pf[g][0] = *(const half8*)&PB[w][g][0][lane << 3];
      pf[g][1] = *(const half8*)&PB[w][g][1][lane << 3];
    }

    // ---- O^T += V^T P^T : V A-frags shared across both q-groups ----
#pragma unroll
    for (int nc = 0; nc < 8; ++nc) {
      int d = nc * 16 + l15;
      half8 v0 = *(const half8*)&Vsm[p][d * 64 + ((quad ^ (d & 7)) << 3)];
      half8 v1 = *(const half8*)&Vsm[p][d * 64 + (((4 + quad) ^ (d & 7)) << 3)];
      oacc[0][nc] = MFMA16(v0, pf[0][0], oacc[0][nc]);
      oacc[0][nc] = MFMA16(v1, pf[0][1], oacc[0][nc]);
      oacc[1][nc] = MFMA16(v0, pf[1][0], oacc[1][nc]);
      oacc[1][nc] = MFMA16(v1, pf[1][1], oacc[1][nc]);
    }
  }

  // ---- epilogue: cross-quad l reduction, normalize, packed stores ----
#pragma unroll
  for (int g = 0; g < 2; ++g) {
    float lr = l_r[g];
    lr += __shfl_xor(lr, 16, 64);
    lr += __shfl_xor(lr, 32, 64);
    float inv = 1.0f / lr;
    int qi = qw0 + g * 16 + l15;
    _Float16* orow = Oh + (size_t)(b * S_LEN + qi) * EMB + h * HD;
#pragma unroll
    for (int nc = 0; nc < 8; ++nc) {
      half4 o4;
#pragma unroll
      for (int r = 0; r < 4; ++r) o4[r] = (_Float16)(oacc[g][nc][r] * inv);
      *(half4*)&orow[nc * 16 + quad * 4] = o4;
    }
  }
}

// ---------------------------------------------------------------------------
// Output projection v2: BK=32 double-buffered single-barrier (same as qkv).
// ---------------------------------------------------------------------------
__global__ __launch_bounds__(256)
void out_gemm(const _Float16* __restrict__ A, const _Float16* __restrict__ B,
              float* __restrict__ out) {
  __shared__ _Float16 Asm[2][128 * 32];
  __shared__ _Float16 Bsm[2][128 * 32];
  const int K = EMB;
  int m0 = blockIdx.y * 128, n0 = blockIdx.x * 128;
  int t = threadIdx.x, lane = t & 63, w = t >> 6;
  int l15 = lane & 15, quad = lane >> 4;
  int wm = (w >> 1) * 64, wn = (w & 1) * 64;

  auto stage = [&](int kt, int p) {
#pragma unroll
    for (int i = 0; i < 2; ++i) {
      int u = t + 256 * i;
      int row = u >> 2, cc = u & 3, g = cc ^ (row & 3);
      gload16(A + (size_t)(m0 + row) * K + kt + g * 8, (char*)Asm[p] + (size_t)u * 16);
      gload16(B + (size_t)(n0 + row) * K + kt + g * 8, (char*)Bsm[p] + (size_t)u * 16);
    }
  };

  f32x4 acc[4][4] = {};
  stage(0, 0);
  for (int it = 0; it < 64; ++it) {
    int p = it & 1;
    __syncthreads();
    if (it < 63) stage((it + 1) * 32, 1 - p);
    half8 af[4], bf[4];
#pragma unroll
    for (int i = 0; i < 4; ++i) {
      int row = wm + i * 16 + l15;
      af[i] = *(const half8*)&Asm[p][row * 32 + ((quad ^ (row & 3)) << 3)];
    }
#pragma unroll
    for (int i = 0; i < 4; ++i) {
      int row = wn + i * 16 + l15;
      bf[i] = *(const half8*)&Bsm[p][row * 32 + ((quad ^ (row & 3)) << 3)];
    }
#pragma unroll
    for (int mi = 0; mi < 4; ++mi)
#pragma unroll
      for (int ni = 0; ni < 4; ++ni)
        acc[mi][ni] = MFMA16(af[mi], bf[ni], acc[mi][ni]);
  }
#pragma unroll
  for (int mi = 0; mi < 4; ++mi)
#pragma unroll
    for (int ni = 0; ni < 4; ++ni)
#pragma unroll
      for (int r = 0; r < 4; ++r) {
        int row = m0 + wm + mi * 16 + quad * 4 + r;
        int col = n0 + wn + ni * 16 + l15;
        out[(size_t)row * EMB + col] = acc[mi][ni][r];
      }
}

extern "C" void kernel_launch(void* const* d_in, const int* in_sizes, int n_in,
                              void* d_out, int out_size, void* d_ws, size_t ws_size,
                              hipStream_t stream) {
  const float* x    = (const float*)d_in[0];
  const float* cosT = (const float*)d_in[1];
  const float* sinT = (const float*)d_in[2];
  const float* Wq   = (const float*)d_in[3];
  const float* Wk   = (const float*)d_in[4];
  const float* Wv   = (const float*)d_in[5];
  const float* Wo   = (const float*)d_in[6];
  float* out = (float*)d_out;

  char* ws = (char*)d_ws;
  _Float16* x16  = (_Float16*)(ws);              // 16 MiB (input to qkv only)
  _Float16* Wq16 = (_Float16*)(ws + 16777216);   //  8 MiB
  _Float16* Wk16 = (_Float16*)(ws + 25165824);   //  2 MiB
  _Float16* Wv16 = (_Float16*)(ws + 27262976);   //  2 MiB
  _Float16* Wo16 = (_Float16*)(ws + 29360128);   //  8 MiB
  _Float16* Qh   = (_Float16*)(ws + 37748736);   // 16 MiB; Oh aliases (block-local)
  _Float16* Kr   = (_Float16*)(ws + 54525952);   //  4 MiB head-major
  _Float16* Vt   = (_Float16*)(ws + 58720256);   //  4 MiB V^T [d][s] (direct from qkv)
  _Float16* Oh   = Qh;                           // alias: block-local overwrite

  convert_all<<<dim3(9216), 256, 0, stream>>>(x, Wq, Wk, Wv, Wo, (_Float16*)ws);
  qkv_gemm<<<dim3(24, 32), 256, 0, stream>>>(x16, Wq16, Wk16, Wv16, Qh, Kr, Vt);
  rope_k<<<dim3(512), 256, 0, stream>>>(Kr, cosT, sinT);
  attn_fused<<<dim3(512), 256, 0, stream>>>(Qh, Kr, Vt, cosT, sinT, Oh);
  out_gemm<<<dim3(16, 32), 256, 0, stream>>>(Oh, Wo16, out);
}

// Round 6
// 278.752 us; speedup vs baseline: 1.0889x; 1.0889x over previous
//
#include <hip/hip_runtime.h>

#define S_LEN 2048
#define EMB 2048
#define NH 16
#define NKV 4
#define HD 128
#define WINDOW 1024
#define BATCH 2

typedef _Float16 half8 __attribute__((ext_vector_type(8)));
typedef _Float16 half4 __attribute__((ext_vector_type(4)));
typedef float f32x4 __attribute__((ext_vector_type(4)));

#define MFMA16(a, b, c) __builtin_amdgcn_mfma_f32_16x16x32_f16((a), (b), (c), 0, 0, 0)

// async 16B global->LDS (DMA, no VGPR roundtrip). Used by attn only.
__device__ __forceinline__ void gload16(const void* g, void* l) {
  __builtin_amdgcn_global_load_lds(
      (const __attribute__((address_space(1))) unsigned int*)g,
      (__attribute__((address_space(3))) unsigned int*)l, 16, 0, 0);
}

// ---------------------------------------------------------------------------
// One-shot fp32 -> fp16 convert of x, Wq, Wk, Wv, Wo into ws.
// ---------------------------------------------------------------------------
__global__ __launch_bounds__(256)
void convert_all(const float* __restrict__ x, const float* __restrict__ wq,
                 const float* __restrict__ wk, const float* __restrict__ wv,
                 const float* __restrict__ wo, _Float16* __restrict__ dst) {
  size_t i = (size_t)blockIdx.x * 256 + threadIdx.x;  // 8-elem unit index
  const float* src; size_t u; size_t dbase;
  if (i < 1048576)      { src = x;  u = i;           dbase = 0; }
  else if (i < 1572864) { src = wq; u = i - 1048576; dbase = 8388608; }
  else if (i < 1703936) { src = wk; u = i - 1572864; dbase = 12582912; }
  else if (i < 1835008) { src = wv; u = i - 1703936; dbase = 13631488; }
  else                  { src = wo; u = i - 1835008; dbase = 14680064; }
  f32x4 a = *(const f32x4*)(src + u * 8);
  f32x4 b = *(const f32x4*)(src + u * 8 + 4);
  half8 h = { (_Float16)a[0], (_Float16)a[1], (_Float16)a[2], (_Float16)a[3],
              (_Float16)b[0], (_Float16)b[1], (_Float16)b[2], (_Float16)b[3] };
  *(half8*)(dst + dbase + u * 8) = h;
}

// ---------------------------------------------------------------------------
// Fused QKV GEMM v3: REG-PREFETCH K-loop (hipBLASLt-style). Global loads for
// tile t+1 go to VGPRs during compute of tile t; ds_write after the barrier.
// The implicit vmcnt wait before ds_write lands on loads issued a full
// compute phase earlier -> no DMA drain stall. BK=64, single 32 KB LDS
// buffer, round-4 conflict-free XOR layout (slot j holds chunk j^(row&7)).
// V written DIRECTLY in V^T [d][s] layout, half4 stores (4 consecutive s).
// ---------------------------------------------------------------------------
__global__ __launch_bounds__(256)
void qkv_gemm(const _Float16* __restrict__ x16, const _Float16* __restrict__ Wq16,
              const _Float16* __restrict__ Wk16, const _Float16* __restrict__ Wv16,
              _Float16* __restrict__ Qh, _Float16* __restrict__ Kr,
              _Float16* __restrict__ Vt) {
  __shared__ _Float16 Asm[128 * 64];
  __shared__ _Float16 Bsm[128 * 64];
  const int K = EMB;
  int m0 = blockIdx.y * 128, n0 = blockIdx.x * 128;
  const _Float16* Wp; int c0, sel;
  if (n0 < 2048)      { Wp = Wq16; c0 = n0;        sel = 0; }
  else if (n0 < 2560) { Wp = Wk16; c0 = n0 - 2048; sel = 1; }
  else                { Wp = Wv16; c0 = n0 - 2560; sel = 2; }

  int t = threadIdx.x, lane = t & 63, w = t >> 6;
  int l15 = lane & 15, quad = lane >> 4;
  int wm = (w >> 1) * 64, wn = (w & 1) * 64;

  int srow = t >> 3, sc = t & 7;
  int gc = sc ^ (srow & 7);                 // global chunk fetched into slot sc
  const _Float16* agp = x16 + (size_t)(m0 + srow) * K + gc * 8;
  const _Float16* bgp = Wp + (size_t)(c0 + srow) * K + gc * 8;

  half8 ar[4], br[4];
  auto gload = [&](int kt) {
#pragma unroll
    for (int p = 0; p < 4; ++p) {
      ar[p] = *(const half8*)(agp + (size_t)p * 32 * K + kt);
      br[p] = *(const half8*)(bgp + (size_t)p * 32 * K + kt);
    }
  };

  f32x4 acc[4][4] = {};
  gload(0);
  for (int it = 0; it < 32; ++it) {
    __syncthreads();                        // all waves done reading LDS(it-1)
#pragma unroll
    for (int p = 0; p < 4; ++p) {           // vmcnt wait here: loads are old
      *(half8*)((char*)Asm + p * 4096 + t * 16) = ar[p];
      *(half8*)((char*)Bsm + p * 4096 + t * 16) = br[p];
    }
    __syncthreads();                        // publish tile(it)
    if (it < 31) gload((it + 1) * 64);      // overlaps all compute below
#pragma unroll
    for (int kc = 0; kc < 2; ++kc) {
      half8 af[4], bf[4];
#pragma unroll
      for (int i = 0; i < 4; ++i) {
        int row = wm + i * 16 + l15;
        af[i] = *(const half8*)&Asm[row * 64 + (((kc * 4 + quad) ^ (row & 7)) * 8)];
      }
#pragma unroll
      for (int i = 0; i < 4; ++i) {
        int row = wn + i * 16 + l15;
        bf[i] = *(const half8*)&Bsm[row * 64 + (((kc * 4 + quad) ^ (row & 7)) * 8)];
      }
#pragma unroll
      for (int mi = 0; mi < 4; ++mi)
#pragma unroll
        for (int ni = 0; ni < 4; ++ni)
          acc[mi][ni] = MFMA16(af[mi], bf[ni], acc[mi][ni]);
    }
  }
#pragma unroll
  for (int mi = 0; mi < 4; ++mi)
#pragma unroll
    for (int ni = 0; ni < 4; ++ni) {
      int row0 = m0 + wm + mi * 16 + quad * 4;   // 4 consecutive rows
      int col = c0 + wn + ni * 16 + l15;
      if (sel == 0) {
#pragma unroll
        for (int r = 0; r < 4; ++r)
          Qh[(size_t)(row0 + r) * 2048 + col] = (_Float16)acc[mi][ni][r];
      } else if (sel == 1) {
        int b = row0 >> 11, s = row0 & 2047, kvh = col >> 7, d = col & 127;
#pragma unroll
        for (int r = 0; r < 4; ++r)
          Kr[((size_t)(b * NKV + kvh) * S_LEN + s + r) * HD + d] = (_Float16)acc[mi][ni][r];
      } else {
        int b = row0 >> 11, s = row0 & 2047, kvh = col >> 7, d = col & 127;
        half4 v4;
#pragma unroll
        for (int r = 0; r < 4; ++r) v4[r] = (_Float16)acc[mi][ni][r];
        *(half4*)&Vt[((size_t)(b * NKV + kvh) * HD + d) * S_LEN + s] = v4;  // V^T
      }
    }
}

// ---------------------------------------------------------------------------
// RoPE K in-place (head-major). cos[d+64]==cos[d].
// ---------------------------------------------------------------------------
__global__ __launch_bounds__(256)
void rope_k(_Float16* __restrict__ Kr, const float* __restrict__ cosT,
            const float* __restrict__ sinT) {
  int t = threadIdx.x;
  int row = blockIdx.x * 32 + (t >> 3);   // (b*NKV+kvh)*S + s
  int s = row & (S_LEN - 1);
  int d0 = (t & 7) * 8;
  _Float16* p = Kr + (size_t)row * HD;
  half8 lo = *(half8*)(p + d0);
  half8 hi = *(half8*)(p + d0 + 64);
  float cv[8], sv[8];
  *(f32x4*)&cv[0] = *(const f32x4*)(cosT + (size_t)s * HD + d0);
  *(f32x4*)&cv[4] = *(const f32x4*)(cosT + (size_t)s * HD + d0 + 4);
  *(f32x4*)&sv[0] = *(const f32x4*)(sinT + (size_t)s * HD + d0);
  *(f32x4*)&sv[4] = *(const f32x4*)(sinT + (size_t)s * HD + d0 + 4);
  half8 rlo, rhi;
#pragma unroll
  for (int u = 0; u < 8; ++u) {
    float l = (float)lo[u], h = (float)hi[u];
    rlo[u] = (_Float16)(l * cv[u] - h * sv[u]);
    rhi[u] = (_Float16)(h * cv[u] + l * sv[u]);
  }
  *(half8*)(p + d0) = rlo;
  *(half8*)(p + d0 + 64) = rhi;
}

// ---------------------------------------------------------------------------
// Flash attention v4 (unchanged from round 5): single-barrier pipeline with
// fully double-buffered K/V^T tiles; DMA for t+1 issued right after the
// barrier publishing t, covered by a full tile of compute. P in B-frag-layout
// LDS (conflict-free). Transposed S^T=K Q^T per-lane softmax.
// ---------------------------------------------------------------------------
__global__ __launch_bounds__(256, 2)
void attn_fused(const _Float16* Qh, const _Float16* __restrict__ Kr,
                const _Float16* __restrict__ Vt, const float* __restrict__ cosT,
                const float* __restrict__ sinT, _Float16* Oh) {
  const float SL2E = 0.08838834764831843f * 1.4426950408889634f;
  int c = blockIdx.x & 255, half = blockIdx.x >> 8;
  int h = c & 15, j = c >> 4;
  int qt = half ? (15 - j) : j;            // heavy/light pairing per CU
  int b = half;
  int kvh = h >> 2;
  int q0 = qt * 128;
  int t = threadIdx.x, lane = t & 63, w = t >> 6;
  int l15 = lane & 15, quad = lane >> 4;

  __shared__ _Float16 Ksm[2][64 * 128];    // 2 x 16 KB, swizzled [k][chunk^k]
  __shared__ _Float16 Vsm[2][128 * 64];    // 2 x 16 KB, swizzled [d][chunk^d]
  __shared__ _Float16 PB[4][2][2][64 * 8]; // 16 KB: [wave][grp][chunk][lane*8+j]

  int qw0 = q0 + w * 32;

  // ---- Q B-frags for both groups + RoPE + fold scale*log2e ----
  half8 qf[2][4];
#pragma unroll
  for (int g = 0; g < 2; ++g) {
    int qi = qw0 + g * 16 + l15;
    const _Float16* qrow = Qh + (size_t)(b * S_LEN + qi) * EMB + h * HD;
    const float* crow = cosT + (size_t)qi * HD;
    const float* srow = sinT + (size_t)qi * HD;
    float qv[4][8], cv[2][8], sv[2][8];
#pragma unroll
    for (int kc = 0; kc < 4; ++kc) {
      half8 q8 = *(const half8*)(qrow + kc * 32 + quad * 8);
#pragma unroll
      for (int jj = 0; jj < 8; ++jj) qv[kc][jj] = (float)q8[jj];
    }
#pragma unroll
    for (int kc = 0; kc < 2; ++kc) {
      int d0 = kc * 32 + quad * 8;
      *(f32x4*)&cv[kc][0] = *(const f32x4*)(crow + d0);
      *(f32x4*)&cv[kc][4] = *(const f32x4*)(crow + d0 + 4);
      *(f32x4*)&sv[kc][0] = *(const f32x4*)(srow + d0);
      *(f32x4*)&sv[kc][4] = *(const f32x4*)(srow + d0 + 4);
    }
#pragma unroll
    for (int kc = 0; kc < 4; ++kc)
#pragma unroll
      for (int jj = 0; jj < 8; ++jj) {
        float rot = (kc < 2) ? -qv[kc + 2][jj] : qv[kc - 2][jj];
        qf[g][kc][jj] = (_Float16)((qv[kc][jj] * cv[kc & 1][jj] + rot * sv[kc & 1][jj]) * SL2E);
      }
  }

  const _Float16* khead = Kr + (size_t)(b * NKV + kvh) * S_LEN * HD;
  const _Float16* vhead = Vt + (size_t)(b * NKV + kvh) * HD * S_LEN;

  auto stage = [&](int kt, int p) {
    int k0 = kt * 64;
#pragma unroll
    for (int i = 0; i < 4; ++i) {
      int u = t + 256 * i;
      int r = u >> 4, cc = u & 15;
      gload16(khead + (((size_t)(k0 + r)) << 7) + ((cc ^ (r & 15)) << 3),
              (char*)Ksm[p] + (size_t)u * 16);
    }
#pragma unroll
    for (int i = 0; i < 4; ++i) {
      int u = t + 256 * i;
      int d = u >> 3, cc = u & 7;
      gload16(vhead + (((size_t)d) << 11) + k0 + ((cc ^ (d & 7)) << 3),
              (char*)Vsm[p] + (size_t)u * 16);
    }
  };

  f32x4 oacc[2][8] = {};
  float l_r[2] = {0.f, 0.f};

  int kt_lo = (q0 >= WINDOW) ? ((q0 - (WINDOW - 1)) >> 6) : 0;
  int kt_hi = qt * 2 + 1;

  stage(kt_lo, 0);
  for (int kt = kt_lo; kt <= kt_hi; ++kt) {
    int p = (kt - kt_lo) & 1;
    int k0 = kt * 64;
    __syncthreads();                        // drains DMA(kt); frees buf 1-p
    if (kt < kt_hi) stage(kt + 1, 1 - p);   // overlaps all of compute below

    // ---- S^T = K Q^T : K A-frags from LDS, shared across both q-groups ----
    f32x4 sfr[2][4];
#pragma unroll
    for (int nb = 0; nb < 4; ++nb) {
      int r = nb * 16 + l15;
      half8 kf[4];
#pragma unroll
      for (int dc = 0; dc < 4; ++dc) {
        int cw = dc * 4 + quad;
        kf[dc] = *(const half8*)&Ksm[p][r * 128 + ((cw ^ l15) << 3)];
      }
      f32x4 s0 = {0.f, 0.f, 0.f, 0.f}, s1 = {0.f, 0.f, 0.f, 0.f};
#pragma unroll
      for (int dc = 0; dc < 4; ++dc) {
        s0 = MFMA16(kf[dc], qf[0][dc], s0);
        s1 = MFMA16(kf[dc], qf[1][dc], s1);
      }
      sfr[0][nb] = s0; sfr[1][nb] = s1;
    }

    // ---- mask + exp2 (no max) + per-lane l + P straight to B-frag LDS ----
#pragma unroll
    for (int g = 0; g < 2; ++g) {
      int qi = qw0 + g * 16 + l15;
#pragma unroll
      for (int nb = 0; nb < 4; ++nb) {
        half4 ph;
#pragma unroll
        for (int r = 0; r < 4; ++r) {
          int key = k0 + nb * 16 + quad * 4 + r;
          int dd = qi - key;
          float sv = (dd >= 0 && dd < WINDOW) ? sfr[g][nb][r] : -1e4f;
          float pv = __builtin_amdgcn_exp2f(fminf(sv, 14.0f));
          l_r[g] += pv;
          ph[r] = (_Float16)pv;
        }
        *(half4*)&PB[w][g][nb >> 1]
            [((l15 + 16 * (((nb & 1) << 1) + (quad >> 1))) << 3) + ((quad & 1) << 2)] = ph;
      }
    }

    // ---- P^T B-frags: contiguous half8 per lane ----
    half8 pf[2][2];
#pragma unroll
    for (int g = 0; g < 2; ++g) {
      pf[g][0] = *(const half8*)&PB[w][g][0][lane << 3];
      pf[g][1] = *(const half8*)&PB[w][g][1][lane << 3];
    }

    // ---- O^T += V^T P^T : V A-frags shared across both q-groups ----
#pragma unroll
    for (int nc = 0; nc < 8; ++nc) {
      int d = nc * 16 + l15;
      half8 v0 = *(const half8*)&Vsm[p][d * 64 + ((quad ^ (d & 7)) << 3)];
      half8 v1 = *(const half8*)&Vsm[p][d * 64 + (((4 + quad) ^ (d & 7)) << 3)];
      oacc[0][nc] = MFMA16(v0, pf[0][0], oacc[0][nc]);
      oacc[0][nc] = MFMA16(v1, pf[0][1], oacc[0][nc]);
      oacc[1][nc] = MFMA16(v0, pf[1][0], oacc[1][nc]);
      oacc[1][nc] = MFMA16(v1, pf[1][1], oacc[1][nc]);
    }
  }

  // ---- epilogue: cross-quad l reduction, normalize, packed stores ----
#pragma unroll
  for (int g = 0; g < 2; ++g) {
    float lr = l_r[g];
    lr += __shfl_xor(lr, 16, 64);
    lr += __shfl_xor(lr, 32, 64);
    float inv = 1.0f / lr;
    int qi = qw0 + g * 16 + l15;
    _Float16* orow = Oh + (size_t)(b * S_LEN + qi) * EMB + h * HD;
#pragma unroll
    for (int nc = 0; nc < 8; ++nc) {
      half4 o4;
#pragma unroll
      for (int r = 0; r < 4; ++r) o4[r] = (_Float16)(oacc[g][nc][r] * inv);
      *(half4*)&orow[nc * 16 + quad * 4] = o4;
    }
  }
}

// ---------------------------------------------------------------------------
// Output projection v3: same reg-prefetch K-loop as qkv. out fp32.
// ---------------------------------------------------------------------------
__global__ __launch_bounds__(256)
void out_gemm(const _Float16* __restrict__ A, const _Float16* __restrict__ B,
              float* __restrict__ out) {
  __shared__ _Float16 Asm[128 * 64];
  __shared__ _Float16 Bsm[128 * 64];
  const int K = EMB;
  int m0 = blockIdx.y * 128, n0 = blockIdx.x * 128;
  int t = threadIdx.x, lane = t & 63, w = t >> 6;
  int l15 = lane & 15, quad = lane >> 4;
  int wm = (w >> 1) * 64, wn = (w & 1) * 64;

  int srow = t >> 3, sc = t & 7;
  int gc = sc ^ (srow & 7);
  const _Float16* agp = A + (size_t)(m0 + srow) * K + gc * 8;
  const _Float16* bgp = B + (size_t)(n0 + srow) * K + gc * 8;

  half8 ar[4], br[4];
  auto gload = [&](int kt) {
#pragma unroll
    for (int p = 0; p < 4; ++p) {
      ar[p] = *(const half8*)(agp + (size_t)p * 32 * K + kt);
      br[p] = *(const half8*)(bgp + (size_t)p * 32 * K + kt);
    }
  };

  f32x4 acc[4][4] = {};
  gload(0);
  for (int it = 0; it < 32; ++it) {
    __syncthreads();
#pragma unroll
    for (int p = 0; p < 4; ++p) {
      *(half8*)((char*)Asm + p * 4096 + t * 16) = ar[p];
      *(half8*)((char*)Bsm + p * 4096 + t * 16) = br[p];
    }
    __syncthreads();
    if (it < 31) gload((it + 1) * 64);
#pragma unroll
    for (int kc = 0; kc < 2; ++kc) {
      half8 af[4], bf[4];
#pragma unroll
      for (int i = 0; i < 4; ++i) {
        int row = wm + i * 16 + l15;
        af[i] = *(const half8*)&Asm[row * 64 + (((kc * 4 + quad) ^ (row & 7)) * 8)];
      }
#pragma unroll
      for (int i = 0; i < 4; ++i) {
        int row = wn + i * 16 + l15;
        bf[i] = *(const half8*)&Bsm[row * 64 + (((kc * 4 + quad) ^ (row & 7)) * 8)];
      }
#pragma unroll
      for (int mi = 0; mi < 4; ++mi)
#pragma unroll
        for (int ni = 0; ni < 4; ++ni)
          acc[mi][ni] = MFMA16(af[mi], bf[ni], acc[mi][ni]);
    }
  }
#pragma unroll
  for (int mi = 0; mi < 4; ++mi)
#pragma unroll
    for (int ni = 0; ni < 4; ++ni)
#pragma unroll
      for (int r = 0; r < 4; ++r) {
        int row = m0 + wm + mi * 16 + quad * 4 + r;
        int col = n0 + wn + ni * 16 + l15;
        out[(size_t)row * EMB + col] = acc[mi][ni][r];
      }
}

extern "C" void kernel_launch(void* const* d_in, const int* in_sizes, int n_in,
                              void* d_out, int out_size, void* d_ws, size_t ws_size,
                              hipStream_t stream) {
  const float* x    = (const float*)d_in[0];
  const float* cosT = (const float*)d_in[1];
  const float* sinT = (const float*)d_in[2];
  const float* Wq   = (const float*)d_in[3];
  const float* Wk   = (const float*)d_in[4];
  const float* Wv   = (const float*)d_in[5];
  const float* Wo   = (const float*)d_in[6];
  float* out = (float*)d_out;

  char* ws = (char*)d_ws;
  _Float16* x16  = (_Float16*)(ws);              // 16 MiB (input to qkv only)
  _Float16* Wq16 = (_Float16*)(ws + 16777216);   //  8 MiB
  _Float16* Wk16 = (_Float16*)(ws + 25165824);   //  2 MiB
  _Float16* Wv16 = (_Float16*)(ws + 27262976);   //  2 MiB
  _Float16* Wo16 = (_Float16*)(ws + 29360128);   //  8 MiB
  _Float16* Qh   = (_Float16*)(ws + 37748736);   // 16 MiB; Oh aliases (block-local)
  _Float16* Kr   = (_Float16*)(ws + 54525952);   //  4 MiB head-major
  _Float16* Vt   = (_Float16*)(ws + 58720256);   //  4 MiB V^T [d][s] (direct from qkv)
  _Float16* Oh   = Qh;                           // alias: block-local overwrite

  convert_all<<<dim3(9216), 256, 0, stream>>>(x, Wq, Wk, Wv, Wo, (_Float16*)ws);
  qkv_gemm<<<dim3(24, 32), 256, 0, stream>>>(x16, Wq16, Wk16, Wv16, Qh, Kr, Vt);
  rope_k<<<dim3(512), 256, 0, stream>>>(Kr, cosT, sinT);
  attn_fused<<<dim3(512), 256, 0, stream>>>(Qh, Kr, Vt, cosT, sinT, Oh);
  out_gemm<<<dim3(16, 32), 256, 0, stream>>>(Oh, Wo16, out);
}